// Round 6
// baseline (270.350 us; speedup 1.0000x reference)
//
#include <hip/hip_runtime.h>

// BaggingMaxPool: out[d] = mean_k( max_{r in indices[k,:]} inp[r][d] )
// N=1024 rows, D=100000 cols, K=20 rounds, SELECT_N=256.
//
// Proven structure (rounds 4-5): streaming pass, per-row 20-bit membership
// mask in LDS, dense BRANCHLESS selects (uniform readfirstlane'd mask ->
// cndmask + v_max3), 4-wave row-split per block, LDS cross-wave reduce.
//
// Round-6 delta: split rows across blocks x2 (grid 782 -> 1564 = 6.1
// blocks/CU; 4 waves/SIMD resident vs 3) to kill residual latency stalls.
// Partials ws[2][20][100000] (16 MB) + tiny reduce kernel (~32 MB extra
// traffic ~= 5us). Inner loop unchanged: CHUNK=4 double-buffered float2
// loads, ~95 live VGPR under the 128-VGPR __launch_bounds__(256,4) cap.

#define N_ROWS   1024
#define D_COLS   100000
#define K_ROUNDS 20
#define SEL_N    256
#define NIDX     (K_ROUNDS * SEL_N)   // 5120
#define VEC      2
#define CPB      (64 * VEC)           // 128 cols per block
#define BLOCK    256
#define WAVES    4
#define ROWSPLIT 2
#define RPB      (N_ROWS / ROWSPLIT)  // 512 rows per block
#define RPW      (RPB / WAVES)        // 128 rows per wave
#define CHUNK    4
#define NEG_INF  (-3.402823466e+38f)
#define NCB      ((D_COLS + CPB - 1) / CPB)   // 782 col-blocks

__device__ __forceinline__ void load_chunk(float2 (&v)[CHUNK], unsigned int (&m)[CHUNK],
                                           const float* __restrict__ p,
                                           const unsigned int* smask,
                                           int r0, int base) {
    #pragma unroll
    for (int j = 0; j < CHUNK; ++j) {
        v[j] = *reinterpret_cast<const float2*>(p + (size_t)(r0 + base + j) * D_COLS);
        m[j] = smask[r0 + base + j];
    }
}

__device__ __forceinline__ void process_chunk(const float2 (&v)[CHUNK],
                                              const unsigned int (&mm)[CHUNK],
                                              float2 (&acc)[K_ROUNDS]) {
    const unsigned int s0 = (unsigned int)__builtin_amdgcn_readfirstlane((int)mm[0]);
    const unsigned int s1 = (unsigned int)__builtin_amdgcn_readfirstlane((int)mm[1]);
    const unsigned int s2 = (unsigned int)__builtin_amdgcn_readfirstlane((int)mm[2]);
    const unsigned int s3 = (unsigned int)__builtin_amdgcn_readfirstlane((int)mm[3]);
    #pragma unroll
    for (int k = 0; k < K_ROUNDS; ++k) {
        const unsigned int bit = 1u << k;
        const float a0x = (s0 & bit) ? v[0].x : NEG_INF;
        const float a0y = (s0 & bit) ? v[0].y : NEG_INF;
        const float a1x = (s1 & bit) ? v[1].x : NEG_INF;
        const float a1y = (s1 & bit) ? v[1].y : NEG_INF;
        const float a2x = (s2 & bit) ? v[2].x : NEG_INF;
        const float a2y = (s2 & bit) ? v[2].y : NEG_INF;
        const float a3x = (s3 & bit) ? v[3].x : NEG_INF;
        const float a3y = (s3 & bit) ? v[3].y : NEG_INF;
        acc[k].x = fmaxf(fmaxf(acc[k].x, a0x), a1x);   // -> v_max3
        acc[k].y = fmaxf(fmaxf(acc[k].y, a0y), a1y);
        acc[k].x = fmaxf(fmaxf(acc[k].x, a2x), a3x);
        acc[k].y = fmaxf(fmaxf(acc[k].y, a2y), a3y);
    }
}

__global__ __launch_bounds__(BLOCK, 4) void bagmax_part_kernel(
    const float* __restrict__ inp,
    const int*   __restrict__ indices,
    float*       __restrict__ ws)          // [ROWSPLIT][K_ROUNDS][D_COLS]
{
    __shared__ unsigned int smask[N_ROWS];
    __shared__ float2 part[WAVES - 1][K_ROUNDS][64];   // 30 KB

    const int tid  = threadIdx.x;
    const int lane = tid & 63;
    const int wave = tid >> 6;
    const int rs   = blockIdx.y;           // row-half 0/1

    // --- per-row 20-bit round-membership mask (indices are L2/L3-hot) ---
    for (int i = tid; i < N_ROWS; i += BLOCK) smask[i] = 0u;
    __syncthreads();
    for (int i = tid; i < NIDX; i += BLOCK) {
        atomicOr(&smask[indices[i]], 1u << (i >> 8));   // i>>8 == i/SEL_N
    }
    __syncthreads();

    const int colbase = blockIdx.x * CPB + lane * VEC;
    const int colc    = colbase <= D_COLS - VEC ? colbase : D_COLS - VEC;  // clamp loads
    const float* p    = inp + colc;
    const int r0      = rs * RPB + wave * RPW;

    float2 acc[K_ROUNDS];
    #pragma unroll
    for (int k = 0; k < K_ROUNDS; ++k) acc[k] = make_float2(NEG_INF, NEG_INF);

    // --- stream this wave's 128 rows: 4-row chunks, double-buffered ---
    float2 A[CHUNK], B[CHUNK];
    unsigned int mA[CHUNK], mB[CHUNK];
    load_chunk(A, mA, p, smask, r0, 0);
    #pragma unroll 1
    for (int c = 0; c < RPW; c += 2 * CHUNK) {
        load_chunk(B, mB, p, smask, r0, c + CHUNK);
        process_chunk(A, mA, acc);
        const int nb = (c + 2 * CHUNK <= RPW - CHUNK) ? (c + 2 * CHUNK) : (RPW - CHUNK);
        load_chunk(A, mA, p, smask, r0, nb);   // last iter: redundant reload, never reprocessed
        process_chunk(B, mB, acc);
    }

    // --- cross-wave max reduce in LDS, write this row-half's partial ---
    if (wave > 0) {
        #pragma unroll
        for (int k = 0; k < K_ROUNDS; ++k) part[wave - 1][k][lane] = acc[k];
    }
    __syncthreads();
    if (wave == 0 && colbase <= D_COLS - VEC) {
        #pragma unroll
        for (int k = 0; k < K_ROUNDS; ++k) {
            const float2 p0 = part[0][k][lane];
            const float2 p1 = part[1][k][lane];
            const float2 p2 = part[2][k][lane];
            float2 m;
            m.x = fmaxf(fmaxf(acc[k].x, p0.x), fmaxf(p1.x, p2.x));
            m.y = fmaxf(fmaxf(acc[k].y, p0.y), fmaxf(p1.y, p2.y));
            *reinterpret_cast<float2*>(ws + ((size_t)(rs * K_ROUNDS + k)) * D_COLS + colbase) = m;
        }
    }
}

__global__ __launch_bounds__(BLOCK) void bagmax_final_kernel(
    const float* __restrict__ ws,
    float*       __restrict__ out)
{
    const int t = blockIdx.x * BLOCK + threadIdx.x;
    const int col = t * VEC;
    if (col > D_COLS - VEC) return;

    float sx = 0.f, sy = 0.f;
    #pragma unroll
    for (int k = 0; k < K_ROUNDS; ++k) {
        const float2 w0 = *reinterpret_cast<const float2*>(ws + ((size_t)(0 * K_ROUNDS + k)) * D_COLS + col);
        const float2 w1 = *reinterpret_cast<const float2*>(ws + ((size_t)(1 * K_ROUNDS + k)) * D_COLS + col);
        sx += fmaxf(w0.x, w1.x);
        sy += fmaxf(w0.y, w1.y);
    }
    *reinterpret_cast<float2*>(out + col) =
        make_float2(sx * (1.0f / K_ROUNDS), sy * (1.0f / K_ROUNDS));
}

extern "C" void kernel_launch(void* const* d_in, const int* in_sizes, int n_in,
                              void* d_out, int out_size, void* d_ws, size_t ws_size,
                              hipStream_t stream) {
    const float* inp     = (const float*)d_in[0];
    const int*   indices = (const int*)d_in[1];
    float*       out     = (float*)d_out;
    float*       ws      = (float*)d_ws;   // needs ROWSPLIT*K_ROUNDS*D_COLS*4 = 16 MB

    dim3 grid1(NCB, ROWSPLIT);
    bagmax_part_kernel<<<grid1, BLOCK, 0, stream>>>(inp, indices, ws);

    const int nthr2 = D_COLS / VEC;                     // 50000
    const int grid2 = (nthr2 + BLOCK - 1) / BLOCK;      // 196
    bagmax_final_kernel<<<grid2, BLOCK, 0, stream>>>(ws, out);
}

// Round 7
// 158.545 us; speedup vs baseline: 1.7052x; 1.7052x over previous
//
#include <hip/hip_runtime.h>

// BaggingMaxPool: out[d] = mean_k( max_{r in indices[k,:]} inp[r][d] )
// N=1024 rows, D=100000 cols, K=20 rounds, SELECT_N=256.
//
// Round-7 restructure (kills the recurring acc[20] spill — rounds 1,2,3,6
// all lost to regalloc on a 20-40 VGPR accumulator array):
//   ROUND-MAJOR over an LDS column tile. Block owns 16 cols; stage
//   tile[1024][16] (64 KB) once from HBM (float4, fully unrolled, 16
//   outstanding dwordx4/thread); then walk the raw indices round-by-round
//   (dups idempotent under max -> no mask, no LDS atomics). Wave w owns
//   rounds 5w..5w+4; 16 lanes = 16 cols x 4 entry-chunks of 64; per lane
//   ONE accumulator register; shfl_xor(16,32) chunk-reduce; tiny LDS
//   cross-wave sum. Entry idx: int4 at static offsets (L1-broadcast).
//
// Cost model: compute ~30us LDS-pipe + ~20us VALU (chip-agg), staging
// ~50-65us (200MB HBM + L3 remainder) -> memory/stage bound. 2 blocks/CU
// (LDS-capped): one stages while the other computes.

#define N_ROWS   1024
#define D_COLS   100000
#define K_ROUNDS 20
#define SEL_N    256
#define CPB      16                         // cols per block
#define NBLOCKS  (D_COLS / CPB)             // 6250 (exact)
#define BLOCK    256
#define WAVES    4
#define RNDS_PW  (K_ROUNDS / WAVES)         // 5 rounds per wave
#define NEG_INF  (-3.402823466e+38f)

__global__ __launch_bounds__(BLOCK, 2) void bagmax_kernel(
    const float* __restrict__ inp,
    const int*   __restrict__ indices,
    float*       __restrict__ out)
{
    __shared__ float tile[N_ROWS * CPB];    // 64 KB, row-major [r][c]
    __shared__ float wpart[WAVES][CPB];     // 256 B

    const int tid     = threadIdx.x;
    const int colbase = blockIdx.x * CPB;

    // ---- stage: each thread loads 16 rows' float4 (rows tid/4 + 64*it) ----
    {
        const int ro = tid >> 2;            // 0..63
        const int c4 = (tid & 3) * 4;       // 0,4,8,12
        const float* gp = inp + (size_t)ro * D_COLS + colbase + c4;
        #pragma unroll
        for (int it = 0; it < 16; ++it) {
            const int r = it * 64 + ro;
            const float4 v = *reinterpret_cast<const float4*>(gp + (size_t)it * 64 * D_COLS);
            *reinterpret_cast<float4*>(&tile[r * CPB + c4]) = v;
        }
    }
    __syncthreads();

    // ---- round-major compute ----
    const int lane  = tid & 63;
    const int wave  = tid >> 6;
    const int c     = lane & 15;            // column within tile
    const int chunk = lane >> 4;            // 0..3: entry-chunk of 64

    float rsum = 0.f;
    #pragma unroll 1
    for (int kk = 0; kk < RNDS_PW; ++kk) {
        const int k    = wave * RNDS_PW + kk;
        const int base = k * SEL_N + chunk * 64;
        float acc = NEG_INF;
        #pragma unroll
        for (int i = 0; i < 64; i += 4) {
            const int4 e = *reinterpret_cast<const int4*>(indices + base + i);
            const float a0 = tile[e.x * CPB + c];
            const float a1 = tile[e.y * CPB + c];
            const float a2 = tile[e.z * CPB + c];
            const float a3 = tile[e.w * CPB + c];
            acc = fmaxf(acc, fmaxf(fmaxf(a0, a1), fmaxf(a2, a3)));
        }
        // combine the 4 entry-chunks (lanes c, c+16, c+32, c+48)
        acc = fmaxf(acc, __shfl_xor(acc, 16, 64));
        acc = fmaxf(acc, __shfl_xor(acc, 32, 64));
        rsum += acc;                        // every lane holds the round max
    }
    if (lane < CPB) wpart[wave][lane] = rsum;
    __syncthreads();

    // ---- cross-wave sum (disjoint round sets) + mean, write 16 cols ----
    if (tid < CPB) {
        const float s = wpart[0][tid] + wpart[1][tid] + wpart[2][tid] + wpart[3][tid];
        out[colbase + tid] = s * (1.0f / (float)K_ROUNDS);
    }
}

extern "C" void kernel_launch(void* const* d_in, const int* in_sizes, int n_in,
                              void* d_out, int out_size, void* d_ws, size_t ws_size,
                              hipStream_t stream) {
    const float* inp     = (const float*)d_in[0];
    const int*   indices = (const int*)d_in[1];
    float*       out     = (float*)d_out;

    bagmax_kernel<<<NBLOCKS, BLOCK, 0, stream>>>(inp, indices, out);
}

// Round 8
// 145.916 us; speedup vs baseline: 1.8528x; 1.0866x over previous
//
#include <hip/hip_runtime.h>

// BaggingMaxPool: out[d] = mean_k( max_{r in indices[k,:]} inp[r][d] )
// N=1024 rows, D=100000 cols, K=20 rounds, SELECT_N=256.
//
// Round-major LDS-tile structure (round 7, spill-proof) with ROUND-8 delta:
// compute reads tile rows as ds_read_b128 (4 cols/lane) instead of
// ds_read_b32 (1 col/lane) -> LDS pipe moves 85 B/cyc vs 44 (m134), compute
// drops ~76us -> ~39-50us chip-wide, under the ~55us staging/memory floor.
//
// Layout: block owns 16 cols; tile[1024][16] f32 (64 KB, 64 B/row,
// 16B-aligned units). Stage: proven round-7 pattern (16x dwordx4/thread).
// Compute: 64 lanes = 16 entry-groups x 4 col-units; per round (5/wave):
// 16 idx dwords (4-lane broadcast, L1-hot) then 16 ds_read_b128 folded
// into TWO max chains (halved dep latency); group-combine via shfl_xor
// strides 4/8/16/32; rsum float4/lane. One float4 acc pair per thread ->
// no acc[20] regalloc hazard (rounds 1/2/3/6 all died there).

#define N_ROWS   1024
#define D_COLS   100000
#define K_ROUNDS 20
#define SEL_N    256
#define CPB      16                         // cols per block
#define NBLOCKS  (D_COLS / CPB)             // 6250 (exact)
#define BLOCK    256
#define WAVES    4
#define RNDS_PW  (K_ROUNDS / WAVES)         // 5 rounds per wave
#define NEG_INF  (-3.402823466e+38f)

__global__ __launch_bounds__(BLOCK, 2) void bagmax_kernel(
    const float* __restrict__ inp,
    const int*   __restrict__ indices,
    float*       __restrict__ out)
{
    __shared__ float tile[N_ROWS * CPB];    // 64 KB, row-major, 64 B/row
    __shared__ float wpart[WAVES][CPB];     // 256 B (16B-aligned rows)

    const int tid     = threadIdx.x;
    const int lane    = tid & 63;
    const int wave    = tid >> 6;
    const int colbase = blockIdx.x * CPB;

    // ---- stage: each thread loads 16 rows' float4 (rows tid/4 + 64*it) ----
    {
        const int ro = tid >> 2;            // 0..63
        const int c4 = (tid & 3) * 4;       // 0,4,8,12
        const float* gp = inp + (size_t)ro * D_COLS + colbase + c4;
        #pragma unroll
        for (int it = 0; it < 16; ++it) {
            const int r = it * 64 + ro;
            const float4 v = *reinterpret_cast<const float4*>(gp + (size_t)it * 64 * D_COLS);
            *reinterpret_cast<float4*>(&tile[r * CPB + c4]) = v;
        }
    }
    __syncthreads();

    // ---- round-major compute: 16 entry-groups x 4 col-units per wave ----
    const int g = lane >> 2;                // entry group 0..15
    const int u = lane & 3;                 // col unit: cols u*4..u*4+3

    float4 rsum = make_float4(0.f, 0.f, 0.f, 0.f);
    #pragma unroll 1
    for (int kk = 0; kk < RNDS_PW; ++kk) {
        const int k  = wave * RNDS_PW + kk;
        const int ib = k * SEL_N + g;

        int e[16];
        #pragma unroll
        for (int i = 0; i < 16; ++i) e[i] = indices[ib + i * 16];

        float4 a0 = make_float4(NEG_INF, NEG_INF, NEG_INF, NEG_INF);
        float4 a1 = a0;
        #pragma unroll
        for (int i = 0; i < 16; i += 2) {
            const float4 v0 = *reinterpret_cast<const float4*>(&tile[e[i]     * CPB + u * 4]);
            const float4 v1 = *reinterpret_cast<const float4*>(&tile[e[i + 1] * CPB + u * 4]);
            a0.x = fmaxf(a0.x, v0.x); a0.y = fmaxf(a0.y, v0.y);
            a0.z = fmaxf(a0.z, v0.z); a0.w = fmaxf(a0.w, v0.w);
            a1.x = fmaxf(a1.x, v1.x); a1.y = fmaxf(a1.y, v1.y);
            a1.z = fmaxf(a1.z, v1.z); a1.w = fmaxf(a1.w, v1.w);
        }
        float4 acc;
        acc.x = fmaxf(a0.x, a1.x); acc.y = fmaxf(a0.y, a1.y);
        acc.z = fmaxf(a0.z, a1.z); acc.w = fmaxf(a0.w, a1.w);

        // combine the 16 entry-groups (lane bits 2..5)
        #pragma unroll
        for (int s = 4; s <= 32; s <<= 1) {
            acc.x = fmaxf(acc.x, __shfl_xor(acc.x, s, 64));
            acc.y = fmaxf(acc.y, __shfl_xor(acc.y, s, 64));
            acc.z = fmaxf(acc.z, __shfl_xor(acc.z, s, 64));
            acc.w = fmaxf(acc.w, __shfl_xor(acc.w, s, 64));
        }
        rsum.x += acc.x; rsum.y += acc.y; rsum.z += acc.z; rsum.w += acc.w;
    }

    if (g == 0) *reinterpret_cast<float4*>(&wpart[wave][u * 4]) = rsum;
    __syncthreads();

    // ---- cross-wave sum (disjoint round sets) + mean, write 16 cols ----
    if (tid < CPB) {
        const float s = wpart[0][tid] + wpart[1][tid] + wpart[2][tid] + wpart[3][tid];
        out[colbase + tid] = s * (1.0f / (float)K_ROUNDS);
    }
}

extern "C" void kernel_launch(void* const* d_in, const int* in_sizes, int n_in,
                              void* d_out, int out_size, void* d_ws, size_t ws_size,
                              hipStream_t stream) {
    const float* inp     = (const float*)d_in[0];
    const int*   indices = (const int*)d_in[1];
    float*       out     = (float*)d_out;

    bagmax_kernel<<<NBLOCKS, BLOCK, 0, stream>>>(inp, indices, out);
}

// Round 9
// 116.738 us; speedup vs baseline: 2.3159x; 1.2499x over previous
//
#include <hip/hip_runtime.h>

// BaggingMaxPool: out[d] = mean_k( max_{r in indices[k,:]} inp[r][d] )
// N=1024 rows, D=100000 cols, K=20 rounds, SELECT_N=256.
//
// Round-major LDS-tile structure (rounds 7-8, spill-proof). Round-9 deltas:
//  - idx preloaded ONCE per block into LDS as u16, TRANSPOSED to [k][g][j]
//    so each lane grabs its 16 round-entries with 2 ds_read_b128 (replaces
//    16 per-lane VMEM dword loads per round; kills their L2-latency chains).
//  - 5-round loop fully unrolled: round k+1 tile reads overlap round k's
//    shfl-reduce chain (cross-round ILP).
//  - bijective XCD-chunked blockIdx swizzle (6250 = 8*781+2): consecutive
//    col-tiles land on the same XCD's L2 (64B row-segment locality).
// LDS: 64 KB tile + 10.25 KB idx + 256 B = ~74.6 KB -> 2 blocks/CU.

#define N_ROWS   1024
#define D_COLS   100000
#define K_ROUNDS 20
#define SEL_N    256
#define NIDX     (K_ROUNDS * SEL_N)         // 5120
#define CPB      16                         // cols per block
#define NBLOCKS  (D_COLS / CPB)             // 6250 (exact)
#define BLOCK    256
#define WAVES    4
#define RNDS_PW  (K_ROUNDS / WAVES)         // 5 rounds per wave
#define NXCD     8
#define NEG_INF  (-3.402823466e+38f)

__global__ __launch_bounds__(BLOCK, 2) void bagmax_kernel(
    const float* __restrict__ inp,
    const int*   __restrict__ indices,
    float*       __restrict__ out)
{
    __shared__ float tile[N_ROWS * CPB];                    // 64 KB, 64 B/row
    __shared__ __align__(16) unsigned short sidx[NIDX];     // 10.25 KB
    __shared__ float wpart[WAVES][CPB];                     // 256 B

    const int tid  = threadIdx.x;
    const int lane = tid & 63;
    const int wave = tid >> 6;

    // ---- bijective XCD-chunked swizzle: consecutive wg -> same XCD ----
    const int orig = blockIdx.x;
    const int q    = NBLOCKS / NXCD;        // 781
    const int r8   = NBLOCKS % NXCD;        // 2
    const int xcd  = orig & (NXCD - 1);
    const int slot = orig >> 3;
    const int wg   = (xcd < r8 ? xcd * (q + 1) : r8 * (q + 1) + (xcd - r8) * q) + slot;
    const int colbase = wg * CPB;

    // ---- idx preload: coalesced reads, u16 transposed store [k][g][j] ----
    for (int i = tid; i < NIDX; i += BLOCK) {
        const int p   = i & 255;                            // position in round
        const int dst = (i & ~255) | ((p & 15) << 4) | (p >> 4);  // k*256 + g*16 + j
        sidx[dst] = (unsigned short)indices[i];
    }

    // ---- stage tile: each thread 16 rows' float4 ----
    {
        const int ro = tid >> 2;            // 0..63
        const int c4 = (tid & 3) * 4;       // 0,4,8,12
        const float* gp = inp + (size_t)ro * D_COLS + colbase + c4;
        #pragma unroll
        for (int it = 0; it < 16; ++it) {
            const int r = it * 64 + ro;
            const float4 v = *reinterpret_cast<const float4*>(gp + (size_t)it * 64 * D_COLS);
            *reinterpret_cast<float4*>(&tile[r * CPB + c4]) = v;
        }
    }
    __syncthreads();

    // ---- round-major compute: 16 entry-groups x 4 col-units per wave ----
    const int g = lane >> 2;                // entry group 0..15
    const int u = lane & 3;                 // col unit: cols u*4..u*4+3

    float4 rsum = make_float4(0.f, 0.f, 0.f, 0.f);
    #pragma unroll
    for (int kk = 0; kk < RNDS_PW; ++kk) {
        const int k = wave * RNDS_PW + kk;

        // 16 entries for this (round, group): two b128 reads of u16x8
        const uint4* sp = reinterpret_cast<const uint4*>(&sidx[k * SEL_N + g * 16]);
        const uint4 w0 = sp[0];
        const uint4 w1 = sp[1];
        unsigned int e[16];
        e[0]  = w0.x & 0xFFFFu; e[1]  = w0.x >> 16;
        e[2]  = w0.y & 0xFFFFu; e[3]  = w0.y >> 16;
        e[4]  = w0.z & 0xFFFFu; e[5]  = w0.z >> 16;
        e[6]  = w0.w & 0xFFFFu; e[7]  = w0.w >> 16;
        e[8]  = w1.x & 0xFFFFu; e[9]  = w1.x >> 16;
        e[10] = w1.y & 0xFFFFu; e[11] = w1.y >> 16;
        e[12] = w1.z & 0xFFFFu; e[13] = w1.z >> 16;
        e[14] = w1.w & 0xFFFFu; e[15] = w1.w >> 16;

        float4 a0 = make_float4(NEG_INF, NEG_INF, NEG_INF, NEG_INF);
        float4 a1 = a0;
        #pragma unroll
        for (int i = 0; i < 16; i += 2) {
            const float4 v0 = *reinterpret_cast<const float4*>(&tile[e[i]     * CPB + u * 4]);
            const float4 v1 = *reinterpret_cast<const float4*>(&tile[e[i + 1] * CPB + u * 4]);
            a0.x = fmaxf(a0.x, v0.x); a0.y = fmaxf(a0.y, v0.y);
            a0.z = fmaxf(a0.z, v0.z); a0.w = fmaxf(a0.w, v0.w);
            a1.x = fmaxf(a1.x, v1.x); a1.y = fmaxf(a1.y, v1.y);
            a1.z = fmaxf(a1.z, v1.z); a1.w = fmaxf(a1.w, v1.w);
        }
        float4 acc;
        acc.x = fmaxf(a0.x, a1.x); acc.y = fmaxf(a0.y, a1.y);
        acc.z = fmaxf(a0.z, a1.z); acc.w = fmaxf(a0.w, a1.w);

        // combine the 16 entry-groups (lane bits 2..5)
        #pragma unroll
        for (int s = 4; s <= 32; s <<= 1) {
            acc.x = fmaxf(acc.x, __shfl_xor(acc.x, s, 64));
            acc.y = fmaxf(acc.y, __shfl_xor(acc.y, s, 64));
            acc.z = fmaxf(acc.z, __shfl_xor(acc.z, s, 64));
            acc.w = fmaxf(acc.w, __shfl_xor(acc.w, s, 64));
        }
        rsum.x += acc.x; rsum.y += acc.y; rsum.z += acc.z; rsum.w += acc.w;
    }

    if (g == 0) *reinterpret_cast<float4*>(&wpart[wave][u * 4]) = rsum;
    __syncthreads();

    // ---- cross-wave sum (disjoint round sets) + mean, write 16 cols ----
    if (tid < CPB) {
        const float s = wpart[0][tid] + wpart[1][tid] + wpart[2][tid] + wpart[3][tid];
        out[colbase + tid] = s * (1.0f / (float)K_ROUNDS);
    }
}

extern "C" void kernel_launch(void* const* d_in, const int* in_sizes, int n_in,
                              void* d_out, int out_size, void* d_ws, size_t ws_size,
                              hipStream_t stream) {
    const float* inp     = (const float*)d_in[0];
    const int*   indices = (const int*)d_in[1];
    float*       out     = (float*)d_out;

    bagmax_kernel<<<NBLOCKS, BLOCK, 0, stream>>>(inp, indices, out);
}